// Round 7
// baseline (128.747 us; speedup 1.0000x reference)
//
#include <hip/hip_runtime.h>

// CliffordLayerNorm: per-256-float block, per-grade (popcount) layernorm.
// One wave handles 16 MV blocks (4 lanes each). Lane l (0..3) of a group
// holds the 64 elements m = 16k + 4l + j; popcount(m) = pc(k)+pc(l)+pc(j).
// Per-grade sums reduced with a 2-step Pascal butterfly over the 2 lane bits.
//
// Round-7: asm LOADS only (depth-2 pipeline pinned: asm volatile loads can't
// be sunk by the compiler; counted s_waitcnt vmcnt(16) + sched_barrier(0)
// per learn_hip rule #18). Stores are plain HIP stores: R6's full-asm version
// corrupted output because LLVM's waitcnt pass couldn't see the asm stores
// and reused their data VGPRs while stores were in flight (WAR hazard).
// Counted waits are compiler-interleave-safe: my asm loads always sit oldest
// in the vmcnt queue, so vmcnt(16) can only over-wait, never under-wait.
// NT stores dropped (R1 vs R4/5: +14% WRITE_SIZE, no FETCH benefit).

typedef float f32x4 __attribute__((ext_vector_type(4)));

#define GLOAD(dst, addr, OFF) \
    asm volatile("global_load_dwordx4 %0, %1, off offset:" OFF \
                 : "=v"(dst) : "v"(addr))

#define LOAD16(buf, addr) \
    GLOAD(buf[0],  addr, "0");   GLOAD(buf[1],  addr, "64");  \
    GLOAD(buf[2],  addr, "128"); GLOAD(buf[3],  addr, "192"); \
    GLOAD(buf[4],  addr, "256"); GLOAD(buf[5],  addr, "320"); \
    GLOAD(buf[6],  addr, "384"); GLOAD(buf[7],  addr, "448"); \
    GLOAD(buf[8],  addr, "512"); GLOAD(buf[9],  addr, "576"); \
    GLOAD(buf[10], addr, "640"); GLOAD(buf[11], addr, "704"); \
    GLOAD(buf[12], addr, "768"); GLOAD(buf[13], addr, "832"); \
    GLOAD(buf[14], addr, "896"); GLOAD(buf[15], addr, "960")

static __device__ __forceinline__ float shx(float v, int m) {
    return __shfl_xor(v, m, 64);
}

// Pascal merge over lane bit BM: b[j] = hi ? a[j-1] : a[j] (a[-1]=a[L]=0),
// then a'[j] = b[j] + partner(b[j]). Length L -> L+1.
template <int BM, int L>
static __device__ __forceinline__ void pascal_step(float (&s)[9], float (&q)[9],
                                                   bool hi) {
#pragma unroll
    for (int j = L; j >= 0; --j) {
        float bs = (j == 0) ? (hi ? 0.0f : s[0])
                 : (j == L) ? (hi ? s[L - 1] : 0.0f)
                            : (hi ? s[j - 1] : s[j]);
        float bq = (j == 0) ? (hi ? 0.0f : q[0])
                 : (j == L) ? (hi ? q[L - 1] : 0.0f)
                            : (hi ? q[j - 1] : q[j]);
        s[j] = bs;
        q[j] = bq;
    }
#pragma unroll
    for (int j = 0; j <= L; ++j) {
        s[j] += shx(s[j], BM);
        q[j] += shx(q[j], BM);
    }
}

// Stats + normalize + HIP stores for one task's 16 float4s.
static __device__ __forceinline__ void process_task(
    const f32x4 (&xv)[16], float* __restrict__ out, int blk, int l,
    bool p1, bool p2, bool hi1, bool hi2,
    const float (&wg)[9], const float (&bg)[9])
{
    constexpr int PC[16] = {0,1,1,2,1,2,2,3,1,2,2,3,2,3,3,4};
    const float invc[9] = {1.0f, 0.125f, 1.0f/28.0f, 1.0f/56.0f, 1.0f/70.0f,
                           1.0f/56.0f, 1.0f/28.0f, 0.125f, 1.0f};

    float s[9], q[9];
#pragma unroll
    for (int j = 0; j < 9; ++j) { s[j] = 0.0f; q[j] = 0.0f; }

#define ACC1(v, r) { s[r] += (v); q[r] = fmaf((v), (v), q[r]); }
#pragma unroll
    for (int k = 0; k < 16; ++k) {
        const int r = PC[k];
        ACC1(xv[k][0], r + 0)
        ACC1(xv[k][1], r + 1)
        ACC1(xv[k][2], r + 1)
        ACC1(xv[k][3], r + 2)
    }
#undef ACC1

    pascal_step<1, 7>(s, q, hi1);
    pascal_step<2, 8>(s, q, hi2);

    float scl[9], sft[9];
#pragma unroll
    for (int g = 0; g < 9; ++g) {
        float mean = s[g] * invc[g];
        float var  = fmaf(-mean, mean, q[g] * invc[g]);
        var = fmaxf(var, 0.0f);
        float inv = rsqrtf(var + 1e-5f);
        float sc  = inv * wg[g];
        scl[g] = sc;
        sft[g] = fmaf(-mean, sc, bg[g]);
    }

    // shift down by p = pc(l) in 0..2; only relative grades 0..6 consumed
#pragma unroll
    for (int j = 0; j < 7; ++j) { scl[j] = p2 ? scl[j+2] : scl[j];
                                  sft[j] = p2 ? sft[j+2] : sft[j]; }
#pragma unroll
    for (int j = 0; j < 7; ++j) { scl[j] = p1 ? scl[j+1] : scl[j];
                                  sft[j] = p1 ? sft[j+1] : sft[j]; }

    f32x4* ob = reinterpret_cast<f32x4*>(out) + (size_t)blk * 64;
#pragma unroll
    for (int k = 0; k < 16; ++k) {
        const int r = PC[k];
        f32x4 o;
        o[0] = fmaf(xv[k][0], scl[r + 0], sft[r + 0]);
        o[1] = fmaf(xv[k][1], scl[r + 1], sft[r + 1]);
        o[2] = fmaf(xv[k][2], scl[r + 1], sft[r + 1]);
        o[3] = fmaf(xv[k][3], scl[r + 2], sft[r + 2]);
        ob[4 * k + l] = o;
    }
}

// Fast path: ntask even, one wave per 2 consecutive tasks, asm-pinned loads.
__global__ __launch_bounds__(256) void cliff_ln_flat(
    const float* __restrict__ x, const float* __restrict__ w,
    const float* __restrict__ b, float* __restrict__ out, int nwaves)
{
    const int lane = threadIdx.x & 63;
    const int grp  = lane >> 2;
    const int l    = lane & 3;
    const int p    = __popc(l);
    const bool p1 = (p & 1) != 0, p2 = (p & 2) != 0;
    const bool hi1 = (l & 1) != 0, hi2 = (l & 2) != 0;
    const int wid = (blockIdx.x * blockDim.x + threadIdx.x) >> 6;
    if (wid >= nwaves) return;

    const int tA = wid * 2, tB = tA + 1;
    const int blkA = (tA << 4) + grp;           // blkB = blkA + 16
    // per-lane element base: blk*256 + l*4 floats; k-th load at +k*64 bytes
    const float* pA = x + (size_t)blkA * 256 + l * 4;
    const float* pB = pA + 4096;                // +16 blocks * 256 floats

    // hoist uniform weight/bias before the big load queue
    float wg[9], bg[9];
#pragma unroll
    for (int g = 0; g < 9; ++g) { wg[g] = w[g]; bg[g] = b[g]; }

    f32x4 A[16], B[16];
    LOAD16(A, pA);
    LOAD16(B, pB);

    // 32 asm loads outstanding (plus possible compiler ops, which only makes
    // this wait stricter); retire all but 16 newest -> A complete.
    asm volatile("s_waitcnt vmcnt(16)" ::: "memory");
    __builtin_amdgcn_sched_barrier(0);
    process_task(A, out, blkA, l, p1, p2, hi1, hi2, wg, bg);

    // queue: B's 16 loads (older) + A's 16 HIP stores (newer; pinned above
    // this waitcnt by its "memory" clobber) -> all-but-16 covers B.
    asm volatile("s_waitcnt vmcnt(16)" ::: "memory");
    __builtin_amdgcn_sched_barrier(0);
    process_task(B, out, blkA + 16, l, p1, p2, hi1, hi2, wg, bg);
}

// General fallback: grid-stride, 1 task per wave, pure HIP (correct for any
// shape with nblk % 16 == 0; used only off the bench fast path).
__global__ __launch_bounds__(256) void cliff_ln_loop(
    const float* __restrict__ x, const float* __restrict__ w,
    const float* __restrict__ b, float* __restrict__ out, int ntask)
{
    const int lane = threadIdx.x & 63;
    const int grp  = lane >> 2;
    const int l    = lane & 3;
    const int p    = __popc(l);
    const bool p1 = (p & 1) != 0, p2 = (p & 2) != 0;
    const bool hi1 = (l & 1) != 0, hi2 = (l & 2) != 0;
    const int wave_id     = (blockIdx.x * blockDim.x + threadIdx.x) >> 6;
    const int total_waves = (gridDim.x * blockDim.x) >> 6;

    float wg[9], bg[9];
#pragma unroll
    for (int g = 0; g < 9; ++g) { wg[g] = w[g]; bg[g] = b[g]; }

    for (int task = wave_id; task < ntask; task += total_waves) {
        const int blk = (task << 4) + grp;
        const f32x4* xb = reinterpret_cast<const f32x4*>(x) + (size_t)blk * 64;
        f32x4 A[16];
#pragma unroll
        for (int k = 0; k < 16; ++k) A[k] = xb[4 * k + l];
        process_task(A, out, blk, l, p1, p2, hi1, hi2, wg, bg);
    }
}

extern "C" void kernel_launch(void* const* d_in, const int* in_sizes, int n_in,
                              void* d_out, int out_size, void* d_ws, size_t ws_size,
                              hipStream_t stream) {
    const float* x = (const float*)d_in[0];
    const float* w = (const float*)d_in[1];
    const float* b = (const float*)d_in[2];
    float* out = (float*)d_out;
    const int n = in_sizes[0];
    const int nblk = n / 256;
    const int ntask = nblk / 16;            // 16384 for the bench shape

    if ((nblk % 16 == 0) && (ntask % 2 == 0)) {
        const int nwaves = ntask / 2;       // 8192
        const int wgs = (nwaves + 3) / 4;   // 2048 WGs
        hipLaunchKernelGGL(cliff_ln_flat, dim3(wgs), dim3(256), 0, stream,
                           x, w, b, out, nwaves);
    } else {
        int wgs = (ntask + 3) / 4;
        if (wgs > 8192) wgs = 8192;
        if (wgs < 1) wgs = 1;
        hipLaunchKernelGGL(cliff_ln_loop, dim3(wgs), dim3(256), 0, stream,
                           x, w, b, out, ntask);
    }
}